// Round 13
// baseline (219.925 us; speedup 1.0000x reference)
//
#include <hip/hip_runtime.h>
#include <hip/hip_bf16.h>

#define B_ 32
#define T_ 256
#define D_ 64
#define H_ 128
#define G_ 384   // 3*H

typedef _Float16 half8 __attribute__((ext_vector_type(8)));
typedef _Float16 half4v __attribute__((ext_vector_type(4)));
typedef float float4v __attribute__((ext_vector_type(4)));
typedef int int8v __attribute__((ext_vector_type(8)));

// Fast gate functions on PRE-SCALED inputs (log2e folded into weights/biases):
// s = log2e * x          -> sigmoid(x) = 1/(1+2^-s)
// t = 2*log2e * x        -> tanh(x)    = 1 - 2/(1+2^t)
__device__ __forceinline__ float fsigmoid2(float s){
  return __builtin_amdgcn_rcpf(1.0f + __builtin_amdgcn_exp2f(-s));
}
__device__ __forceinline__ float ftanh2(float t){
  return 1.0f - 2.0f*__builtin_amdgcn_rcpf(1.0f + __builtin_amdgcn_exp2f(t));
}
#define LOG2E  1.442695041f
#define LOG2E2 2.885390082f

// NOTE (R5-R7 post-mortem): inputs/outputs are f32. bf16 misread was the NaN bug.
//
// Structure ledger (measured):
//  - v10 (R10): 4-wave 1-BAR chained f16 MFMA = 1241 cyc/step (132.4 us).
//  - v11-v15: fdot2 line closed. v16 (R17): rcp/exp2 gates = 1105 (117.9).
//  - v17 (R18): 8-wave N-split = ~990 (105.7). v18 (R19): depth-2 6-chain +
//    setprio + waves_per_eu = ~967 (103.1) — f16 champion, reproduced R22.
//  - v19/v20: 12-chain / seeded-C — REGRESSED (acc-init cost; VALU->MFMA
//    hazard on C-input).
//  - v22 (R23): fp8 K=128 mfma_scale (3 MFMA/wave, 8 waves) = ~878 cyc/step
//    (93.6 us, absmax 0.0156 PASSED). Pipe term gone (MfmaUtil 2.5%);
//    remaining ~300-400 cyc = cross-wave skew/arbitration at the barrier
//    (8 waves, 2/SIMD competing for the MFMA pipe every substep).
//  - v23 (R24, this): 4-wave fp8 — wave owns 32 gates (2 tiles x 3 parts =
//    6 MFMA/wave), 1 wave/SIMD: no intra-SIMD pipe competition, half the
//    barrier participants. Gate chain x2/lane (independent, ILP). Tests the
//    skew hypothesis; if regression -> wave-count axis closed, floor found.
#define BAR() do{ asm volatile("s_waitcnt lgkmcnt(0)" ::: "memory"); \
                  __builtin_amdgcn_s_barrier(); \
                  asm volatile("" ::: "memory"); } while(0)

// wcol[b,j] = column sums of the row-normalized adjacency (R1 derivation):
// adj_raw[i,j] = p_i p_j sim_ij + I; rs_i = 1 + p_i*sum_j p_j sim_ij;
// wcol_j = p_j * sum_i p_i sim_ij / rs_i + 1/rs_j  (sim symmetric).
__global__ void __launch_bounds__(256) adj_k(const float* mm, const float* E,
                                             float* wcol){
  int b = blockIdx.x;
  int tid = threadIdx.x;
  int d = tid & 63, q = tid >> 6;
  __shared__ float spp[4][64];
  __shared__ float sp[64];
  __shared__ float sE[64*129];
  __shared__ float ssim[64*65];
  __shared__ float srs[64];
  float p = 0.0f;
  for (int t = q*64; t < q*64+64; t++) p += 1.0f - mm[(b*T_ + t)*D_ + d];
  spp[q][d] = p;
  for (int i = tid; i < D_*H_; i += 256){ int r = i >> 7, c = i & 127; sE[r*129+c] = E[i]; }
  __syncthreads();
  if (tid < 64) sp[tid] = (spp[0][tid]+spp[1][tid]+spp[2][tid]+spp[3][tid]) * (1.0f/T_);
  __syncthreads();
  float rowE[128];
  #pragma unroll
  for (int k = 0; k < 128; k++) rowE[k] = sE[d*129+k];
  for (int i = q*16; i < q*16+16; i++){
    float s = 0.0f;
    #pragma unroll
    for (int k = 0; k < 128; k++) s += rowE[k]*sE[i*129+k];
    ssim[d*65+i] = fmaxf(s, 0.0f);
  }
  __syncthreads();
  if (tid < 64){
    float rs = 0.0f;
    for (int j = 0; j < 64; j++) rs += sp[j]*ssim[tid*65+j];
    srs[tid] = fmaxf(sp[tid]*rs + 1.0f, 1e-6f);
  }
  __syncthreads();
  if (tid < 64){
    float s = 0.0f;
    for (int i = 0; i < 64; i++) s += sp[i]*ssim[tid*65+i]/srs[i];
    wcol[b*64 + tid] = sp[tid]*s + 1.0f/srs[tid];
  }
}

// gi_k v6: gi3 f16; E staged into LDS f16 (pitch 132); Phase-B weights/biases
// pre-scaled by LOG2E (r,z rows) / LOG2E2 (n rows) for exp2 gates.
// Phase A: vr[32t][128h] = (x*(1-mm)*wcol/64)[32t][64d] x E[64d][128h] + time-enc
// Phase B: gi[32t][384g] = vr x (sc*W_ih)^T + sc*(bih + bhh[r,z]); gi3 [b][g][t].
#define AVP 72
#define VRP 136
#define SEP 132
__global__ void __launch_bounds__(512,1) gi_k(const float* x, const float* mm,
                                              const float* vt, const float* E,
                                              const float* wih, const float* bih,
                                              const float* bhh, const float* wcol,
                                              _Float16* gi3){
  int bid = blockIdx.x;
  int b = bid >> 3, t0 = (bid & 7)*32;
  int tid = threadIdx.x;
  int w = tid >> 6, l = tid & 63;
  int lq = l >> 4, lm = l & 15;

  __shared__ __align__(16) _Float16 av[32*AVP];
  __shared__ __align__(16) _Float16 vrA[32*VRP];
  __shared__ __align__(16) _Float16 sEl[64*SEP];
  __shared__ float sVt[32];

  // stage av[t][d] = x*(1-mm)*wcol/64  (f32 in, f16 out)
  {
    int i = tid*4, t = i >> 6, d4 = i & 63;
    long src = (long)(b*T_ + t0 + t)*D_ + d4;
    float4 xv = *(const float4*)&x[src];
    float4 mv = *(const float4*)&mm[src];
    float4 wv = *(const float4*)&wcol[b*D_ + d4];
    half4v h;
    h[0]=(_Float16)(xv.x*(1.0f-mv.x)*wv.x*(1.0f/64));
    h[1]=(_Float16)(xv.y*(1.0f-mv.y)*wv.y*(1.0f/64));
    h[2]=(_Float16)(xv.z*(1.0f-mv.z)*wv.z*(1.0f/64));
    h[3]=(_Float16)(xv.w*(1.0f-mv.w)*wv.w*(1.0f/64));
    *(half4v*)&av[t*AVP + d4] = h;
  }
  // stage E -> LDS f16, coalesced
  {
    int r = tid >> 3, c0 = (tid & 7)*16;
    #pragma unroll
    for (int g = 0; g < 4; g++){
      float4 v = *(const float4*)&E[r*H_ + c0 + g*4];
      half4v h;
      h[0]=(_Float16)v.x; h[1]=(_Float16)v.y; h[2]=(_Float16)v.z; h[3]=(_Float16)v.w;
      *(half4v*)&sEl[r*SEP + c0 + g*4] = h;
    }
  }
  if (tid < 32) sVt[tid] = vt[b*T_ + t0 + tid];
  __syncthreads();

  // Phase A B-frags: B[k=d][n] = E[d][16w+n]  (gather from LDS)
  half8 bE[2];
  #pragma unroll
  for (int kc = 0; kc < 2; kc++){
    half8 f;
    #pragma unroll
    for (int jj = 0; jj < 8; jj++)
      f[jj] = sEl[(kc*32 + lq*8 + jj)*SEP + 16*w + lm];
    bE[kc] = f;
  }

  float4v accA[2] = {{0,0,0,0},{0,0,0,0}};
  #pragma unroll
  for (int kc = 0; kc < 2; kc++){
    #pragma unroll
    for (int mt = 0; mt < 2; mt++){
      half8 a = *(const half8*)&av[(mt*16+lm)*AVP + kc*32 + lq*8];
      accA[mt] = __builtin_amdgcn_mfma_f32_16x16x32_f16(a, bE[kc], accA[mt], 0,0,0);
    }
  }
  {
    int h = 16*w + lm;
    float fr = __expf(-(float)(h & 63) * 0.14391157f);   // ln(1e4)/64
    #pragma unroll
    for (int mt = 0; mt < 2; mt++){
      #pragma unroll
      for (int r = 0; r < 4; r++){
        int tl = mt*16 + lq*4 + r;
        float ang = sVt[tl] * fr;
        float e = (h < 64) ? __sinf(ang) : __cosf(ang);
        vrA[tl*VRP + h] = (_Float16)(accA[mt][r] + e);
      }
    }
  }
  __syncthreads();

  // Phase B: wave owns N-tiles 3w..3w+2; weights/bias pre-scaled for exp2 gates
  half8 bW[3][4]; float biW[3];
  #pragma unroll
  for (int q = 0; q < 3; q++){
    int g = 16*(3*w + q) + lm;
    float sc = (g < 2*H_) ? LOG2E : LOG2E2;
    biW[q] = (bih[g] + (g < 2*H_ ? bhh[g] : 0.0f)) * sc;  // fold b_hh for r,z
    #pragma unroll
    for (int kc = 0; kc < 4; kc++){
      const float* src = &wih[(long)g*H_ + kc*32 + lq*8];
      float4 x0 = *(const float4*)src;
      float4 x1 = *(const float4*)(src+4);
      half8 f;
      f[0]=(_Float16)(x0.x*sc); f[1]=(_Float16)(x0.y*sc); f[2]=(_Float16)(x0.z*sc); f[3]=(_Float16)(x0.w*sc);
      f[4]=(_Float16)(x1.x*sc); f[5]=(_Float16)(x1.y*sc); f[6]=(_Float16)(x1.z*sc); f[7]=(_Float16)(x1.w*sc);
      bW[q][kc] = f;
    }
  }
  float4v cB[2][3];
  #pragma unroll
  for (int mt = 0; mt < 2; mt++)
    #pragma unroll
    for (int q = 0; q < 3; q++) cB[mt][q] = (float4v){0,0,0,0};
  #pragma unroll
  for (int kc = 0; kc < 4; kc++){
    #pragma unroll
    for (int mt = 0; mt < 2; mt++){
      half8 a = *(const half8*)&vrA[(mt*16+lm)*VRP + kc*32 + lq*8];
      #pragma unroll
      for (int q = 0; q < 3; q++)
        cB[mt][q] = __builtin_amdgcn_mfma_f32_16x16x32_f16(a, bW[q][kc], cB[mt][q], 0,0,0);
    }
  }
  #pragma unroll
  for (int mt = 0; mt < 2; mt++){
    #pragma unroll
    for (int q = 0; q < 3; q++){
      int g = 16*(3*w + q) + lm;
      int tb = t0 + mt*16 + lq*4;
      half4v hv;
      hv[0]=(_Float16)(cB[mt][q][0] + biW[q]); hv[1]=(_Float16)(cB[mt][q][1] + biW[q]);
      hv[2]=(_Float16)(cB[mt][q][2] + biW[q]); hv[3]=(_Float16)(cB[mt][q][3] + biW[q]);
      *(half4v*)&gi3[((long)(b*G_ + g))*T_ + tb] = hv;
    }
  }
}

// Sequential GRU v23 (R24): 4-wave fp8 K=128 recurrence. Wave w owns gates
// [32w, 32w+32) as two 16-col tiles; 6 MFMAs/wave/substep, 1 wave/SIMD (no
// intra-SIMD MFMA-pipe competition, 4 barrier participants instead of 8).
// Lane lm handles gate pair (j0=32w+lm, j1=j0+16): two independent gate
// chains (ILP through the trans pipe). h/W in e4m3 stored x16, uniform e8m0
// scale 2^-4 per operand (identical lane->k map on A and B, permutation
// cancels). Zero-init C (R21 hazard lesson). One LDS-only BAR per step,
// fp8 hb[2][128] ping-pong, named A/B gi prefetch regs (12 half8).
__global__ void __attribute__((amdgpu_waves_per_eu(1, 1)))
__launch_bounds__(256) gru_k(const _Float16* gi3, const float* whh,
                             const float* bhh, const int* lengths,
                             float* out){
  int b = blockIdx.x;
  int tid = threadIdx.x;
  int w = tid >> 6, l = tid & 63;
  int lq = l >> 4, lm = l & 15;
  int j0 = 32*w + lm;            // first gate owned (valid for all lanes)
  int j1 = j0 + 16;              // second gate owned
  bool gate = (l < 16);
  int len = lengths[b];

  __shared__ __align__(32) unsigned char hb8[2][H_];

  // B-frags (fp8): [q][t], q=0 r, 1 z, 2 n; tile t covers gates 32w+16t+lm.
  // byte i of lane (lq,lm) = e4m3(16*sc*W_hh[q*H+32w+16t+lm][lq*32+i])
  int8v bf8[3][2];
  #pragma unroll
  for (int q = 0; q < 3; q++){
    float sc16 = ((q == 2) ? LOG2E2 : LOG2E) * 16.0f;
    #pragma unroll
    for (int t = 0; t < 2; t++){
      int row = q*H_ + 32*w + t*16 + lm;
      const float* src = &whh[(long)row*H_ + lq*32];
      int8v f;
      #pragma unroll
      for (int d = 0; d < 8; d++){
        float4 v = *(const float4*)(src + d*4);
        int pk = __builtin_amdgcn_cvt_pk_fp8_f32(v.x*sc16, v.y*sc16, 0, false);
        pk = __builtin_amdgcn_cvt_pk_fp8_f32(v.z*sc16, v.w*sc16, pk, true);
        f[d] = pk;
      }
      bf8[q][t] = f;
    }
  }
  float bn0 = bhh[2*H_ + j0] * LOG2E2;
  float bn1 = bhh[2*H_ + j1] * LOG2E2;
  const _Float16* pr0 = gi3 + ((long)b*G_ + j0)*T_;
  const _Float16* pz0 = pr0 + (long)H_*T_;
  const _Float16* pn0 = pr0 + (long)2*H_*T_;
  const _Float16* pr1 = gi3 + ((long)b*G_ + j1)*T_;
  const _Float16* pz1 = pr1 + (long)H_*T_;
  const _Float16* pn1 = pr1 + (long)2*H_*T_;

  if (tid < H_){ hb8[0][tid] = 0; hb8[1][tid] = 0; }

  // gi prefetch: named double-buffer registers, static indexing only
  half8 prA0, pzA0, pnA0, prB0, pzB0, pnB0;
  half8 prA1, pzA1, pnA1, prB1, pzB1, pnB1;
  prA0 = *(const half8*)pr0; pzA0 = *(const half8*)pz0; pnA0 = *(const half8*)pn0;
  prA1 = *(const half8*)pr1; pzA1 = *(const half8*)pz1; pnA1 = *(const half8*)pn1;
  __syncthreads();   // cold path: full barrier fine

  float hv0 = 0.0f, hv1 = 0.0f;

  auto substeps = [&](half8 cr0, half8 cz0, half8 cn0,
                      half8 cr1, half8 cz1, half8 cn1, int c){
    float ho0[8], ho1[8];
    #pragma unroll
    for (int i = 0; i < 8; i++){
      const int rp = i & 1;            // read hb8[rp], write hb8[rp^1]
      int8v av = *(const int8v*)&hb8[rp][lq*32];   // 32 B broadcast per lq group
      float4v c0a = {0,0,0,0}, c0b = {0,0,0,0};
      float4v c1a = {0,0,0,0}, c1b = {0,0,0,0};
      float4v c2a = {0,0,0,0}, c2b = {0,0,0,0};
      __builtin_amdgcn_s_setprio(1);
      // scale_sel=0, scale=123 (e8m0 2^-4) per operand: (16h)(16w)*2^-8 = h*w
      c0a = __builtin_amdgcn_mfma_scale_f32_16x16x128_f8f6f4(av, bf8[0][0], c0a, 0, 0, 0, 123, 0, 123);
      c0b = __builtin_amdgcn_mfma_scale_f32_16x16x128_f8f6f4(av, bf8[0][1], c0b, 0, 0, 0, 123, 0, 123);
      c1a = __builtin_amdgcn_mfma_scale_f32_16x16x128_f8f6f4(av, bf8[1][0], c1a, 0, 0, 0, 123, 0, 123);
      c1b = __builtin_amdgcn_mfma_scale_f32_16x16x128_f8f6f4(av, bf8[1][1], c1b, 0, 0, 0, 123, 0, 123);
      c2a = __builtin_amdgcn_mfma_scale_f32_16x16x128_f8f6f4(av, bf8[2][0], c2a, 0, 0, 0, 123, 0, 123);
      c2b = __builtin_amdgcn_mfma_scale_f32_16x16x128_f8f6f4(av, bf8[2][1], c2b, 0, 0, 0, 123, 0, 123);
      __builtin_amdgcn_s_setprio(0);
      float r0 = fsigmoid2((float)cr0[i] + c0a[0]);
      float r1 = fsigmoid2((float)cr1[i] + c0b[0]);
      float z0 = fsigmoid2((float)cz0[i] + c1a[0]);
      float z1 = fsigmoid2((float)cz1[i] + c1b[0]);
      float n0 = ftanh2((float)cn0[i] + r0*(c2a[0] + bn0));
      float n1 = ftanh2((float)cn1[i] + r1*(c2b[0] + bn1));
      hv0 = (1.0f - z0)*n0 + z0*hv0;
      hv1 = (1.0f - z1)*n1 + z1*hv1;
      if (gate){
        int hq0 = __builtin_amdgcn_cvt_pk_fp8_f32(hv0*16.0f, hv0*16.0f, 0, false);
        int hq1 = __builtin_amdgcn_cvt_pk_fp8_f32(hv1*16.0f, hv1*16.0f, 0, false);
        hb8[rp^1][j0] = (unsigned char)(hq0 & 0xff);
        hb8[rp^1][j1] = (unsigned char)(hq1 & 0xff);
        ho0[i] = (c*8 + i < len) ? hv0 : 0.0f;
        ho1[i] = (c*8 + i < len) ? hv1 : 0.0f;
      }
      BAR();
    }
    if (gate){
      long ob = ((long)b*T_ + c*8)*H_;
      #pragma unroll
      for (int i = 0; i < 8; i++){
        out[ob + (long)i*H_ + j0] = ho0[i];
        out[ob + (long)i*H_ + j1] = ho1[i];
      }
    }
  };

  for (int c = 0; c < 32; c += 2){
    {
      int nb = (c+1)*8;
      prB0 = *(const half8*)(pr0+nb); pzB0 = *(const half8*)(pz0+nb); pnB0 = *(const half8*)(pn0+nb);
      prB1 = *(const half8*)(pr1+nb); pzB1 = *(const half8*)(pz1+nb); pnB1 = *(const half8*)(pn1+nb);
    }
    substeps(prA0, pzA0, pnA0, prA1, pzA1, pnA1, c);
    if (c+2 < 32){
      int nb = (c+2)*8;
      prA0 = *(const half8*)(pr0+nb); pzA0 = *(const half8*)(pz0+nb); pnA0 = *(const half8*)(pn0+nb);
      prA1 = *(const half8*)(pr1+nb); pzA1 = *(const half8*)(pz1+nb); pnA1 = *(const half8*)(pn1+nb);
    }
    substeps(prB0, pzB0, pnB0, prB1, pzB1, pnB1, c+1);
  }
}

extern "C" void kernel_launch(void* const* d_in, const int* in_sizes, int n_in,
                              void* d_out, int out_size, void* d_ws, size_t ws_size,
                              hipStream_t stream) {
  char* base = (char*)d_ws;
  size_t off = 0;
  auto alloc = [&](size_t bytes)->void*{
    void* p = base + off; off = (off + bytes + 255) & ~(size_t)255; return p;
  };
  float*     wcol = (float*)alloc((size_t)B_*D_*4);
  _Float16*  gi3  = (_Float16*)alloc((size_t)B_*G_*T_*2);
  if (off > ws_size) return;

  const float* x   = (const float*)d_in[0];
  const float* mm  = (const float*)d_in[1];
  const float* vt  = (const float*)d_in[2];
  const int*   len = (const int*)d_in[4];
  const float* E   = (const float*)d_in[5];
  const float* wih = (const float*)d_in[6];
  const float* whh = (const float*)d_in[7];
  const float* bih = (const float*)d_in[8];
  const float* bhh = (const float*)d_in[9];

  adj_k<<<dim3(B_),dim3(256),0,stream>>>(mm, E, wcol);
  gi_k<<<dim3(256),dim3(512),0,stream>>>(x, mm, vt, E, wih, bih, bhh, wcol, gi3);
  gru_k<<<dim3(B_),dim3(256),0,stream>>>(gi3, whh, bhh, len, (float*)d_out);
}

// Round 14
// 216.173 us; speedup vs baseline: 1.0174x; 1.0174x over previous
//
#include <hip/hip_runtime.h>
#include <hip/hip_bf16.h>

#define B_ 32
#define T_ 256
#define D_ 64
#define H_ 128
#define G_ 384   // 3*H

typedef _Float16 half8 __attribute__((ext_vector_type(8)));
typedef _Float16 half4v __attribute__((ext_vector_type(4)));
typedef float float4v __attribute__((ext_vector_type(4)));
typedef int int8v __attribute__((ext_vector_type(8)));

// Fast gate functions on PRE-SCALED inputs (log2e folded into weights/biases):
// s = log2e * x          -> sigmoid(x) = 1/(1+2^-s)
// t = 2*log2e * x        -> tanh(x)    = 1 - 2/(1+2^t)
__device__ __forceinline__ float fsigmoid2(float s){
  return __builtin_amdgcn_rcpf(1.0f + __builtin_amdgcn_exp2f(-s));
}
__device__ __forceinline__ float ftanh2(float t){
  return 1.0f - 2.0f*__builtin_amdgcn_rcpf(1.0f + __builtin_amdgcn_exp2f(t));
}
#define LOG2E  1.442695041f
#define LOG2E2 2.885390082f

// NOTE (R5-R7 post-mortem): inputs/outputs are f32. bf16 misread was the NaN bug.
//
// Structure ledger (measured, FINAL):
//  - v10: 4-wave f16 MFMA = 1241 cyc/step (132.4 us).
//  - v11-v15: fdot2 line CLOSED (allocator remat/spill, best 139.4).
//  - v16: rcp/exp2 gates + log2e prefold = 1105 (117.9).
//  - v17: 8-wave N-split = ~990 (105.7). v18: depth-2 + setprio + wpe(2,2)
//    = ~967 (103.1) — f16 champion, reproduced R22.
//  - v19/v20: 12-chain / seeded-C REGRESSED (acc-init; VALU->MFMA hazard).
//  - v22 (R23): fp8 K=128 mfma_scale, 8 waves = ~878 cyc/step (93.6 us,
//    absmax 0.0156 PASSED) — CHAMPION.
//  - v23 (R24): 4-wave fp8 = ~1040 REGRESSION. Sibling wave per SIMD HIDES
//    latency, doesn't just compete. Wave axis closed: 8 optimal both
//    precisions; >8 impossible (24 tiles / 3-per-wave lane-local triple).
//  - v24 (R25, this): v22 verbatim revert. Serial chain arithmetic:
//    bar->ds_read(120)->3xMFMA(145)->gates(80)->cvt+write+wait(60)->bar(30)
//    = 435; x2-wave pipe/VALU share + skew = 700-850 vs measured 878.
//    This is a 256-step serial-recurrence LATENCY floor, not a roofline.
#define BAR() do{ asm volatile("s_waitcnt lgkmcnt(0)" ::: "memory"); \
                  __builtin_amdgcn_s_barrier(); \
                  asm volatile("" ::: "memory"); } while(0)

// wcol[b,j] = column sums of the row-normalized adjacency (R1 derivation):
// adj_raw[i,j] = p_i p_j sim_ij + I; rs_i = 1 + p_i*sum_j p_j sim_ij;
// wcol_j = p_j * sum_i p_i sim_ij / rs_i + 1/rs_j  (sim symmetric).
__global__ void __launch_bounds__(256) adj_k(const float* mm, const float* E,
                                             float* wcol){
  int b = blockIdx.x;
  int tid = threadIdx.x;
  int d = tid & 63, q = tid >> 6;
  __shared__ float spp[4][64];
  __shared__ float sp[64];
  __shared__ float sE[64*129];
  __shared__ float ssim[64*65];
  __shared__ float srs[64];
  float p = 0.0f;
  for (int t = q*64; t < q*64+64; t++) p += 1.0f - mm[(b*T_ + t)*D_ + d];
  spp[q][d] = p;
  for (int i = tid; i < D_*H_; i += 256){ int r = i >> 7, c = i & 127; sE[r*129+c] = E[i]; }
  __syncthreads();
  if (tid < 64) sp[tid] = (spp[0][tid]+spp[1][tid]+spp[2][tid]+spp[3][tid]) * (1.0f/T_);
  __syncthreads();
  float rowE[128];
  #pragma unroll
  for (int k = 0; k < 128; k++) rowE[k] = sE[d*129+k];
  for (int i = q*16; i < q*16+16; i++){
    float s = 0.0f;
    #pragma unroll
    for (int k = 0; k < 128; k++) s += rowE[k]*sE[i*129+k];
    ssim[d*65+i] = fmaxf(s, 0.0f);
  }
  __syncthreads();
  if (tid < 64){
    float rs = 0.0f;
    for (int j = 0; j < 64; j++) rs += sp[j]*ssim[tid*65+j];
    srs[tid] = fmaxf(sp[tid]*rs + 1.0f, 1e-6f);
  }
  __syncthreads();
  if (tid < 64){
    float s = 0.0f;
    for (int i = 0; i < 64; i++) s += sp[i]*ssim[tid*65+i]/srs[i];
    wcol[b*64 + tid] = sp[tid]*s + 1.0f/srs[tid];
  }
}

// gi_k v6: gi3 f16; E staged into LDS f16 (pitch 132); Phase-B weights/biases
// pre-scaled by LOG2E (r,z rows) / LOG2E2 (n rows) for exp2 gates.
// Phase A: vr[32t][128h] = (x*(1-mm)*wcol/64)[32t][64d] x E[64d][128h] + time-enc
// Phase B: gi[32t][384g] = vr x (sc*W_ih)^T + sc*(bih + bhh[r,z]); gi3 [b][g][t].
#define AVP 72
#define VRP 136
#define SEP 132
__global__ void __launch_bounds__(512,1) gi_k(const float* x, const float* mm,
                                              const float* vt, const float* E,
                                              const float* wih, const float* bih,
                                              const float* bhh, const float* wcol,
                                              _Float16* gi3){
  int bid = blockIdx.x;
  int b = bid >> 3, t0 = (bid & 7)*32;
  int tid = threadIdx.x;
  int w = tid >> 6, l = tid & 63;
  int lq = l >> 4, lm = l & 15;

  __shared__ __align__(16) _Float16 av[32*AVP];
  __shared__ __align__(16) _Float16 vrA[32*VRP];
  __shared__ __align__(16) _Float16 sEl[64*SEP];
  __shared__ float sVt[32];

  // stage av[t][d] = x*(1-mm)*wcol/64  (f32 in, f16 out)
  {
    int i = tid*4, t = i >> 6, d4 = i & 63;
    long src = (long)(b*T_ + t0 + t)*D_ + d4;
    float4 xv = *(const float4*)&x[src];
    float4 mv = *(const float4*)&mm[src];
    float4 wv = *(const float4*)&wcol[b*D_ + d4];
    half4v h;
    h[0]=(_Float16)(xv.x*(1.0f-mv.x)*wv.x*(1.0f/64));
    h[1]=(_Float16)(xv.y*(1.0f-mv.y)*wv.y*(1.0f/64));
    h[2]=(_Float16)(xv.z*(1.0f-mv.z)*wv.z*(1.0f/64));
    h[3]=(_Float16)(xv.w*(1.0f-mv.w)*wv.w*(1.0f/64));
    *(half4v*)&av[t*AVP + d4] = h;
  }
  // stage E -> LDS f16, coalesced
  {
    int r = tid >> 3, c0 = (tid & 7)*16;
    #pragma unroll
    for (int g = 0; g < 4; g++){
      float4 v = *(const float4*)&E[r*H_ + c0 + g*4];
      half4v h;
      h[0]=(_Float16)v.x; h[1]=(_Float16)v.y; h[2]=(_Float16)v.z; h[3]=(_Float16)v.w;
      *(half4v*)&sEl[r*SEP + c0 + g*4] = h;
    }
  }
  if (tid < 32) sVt[tid] = vt[b*T_ + t0 + tid];
  __syncthreads();

  // Phase A B-frags: B[k=d][n] = E[d][16w+n]  (gather from LDS)
  half8 bE[2];
  #pragma unroll
  for (int kc = 0; kc < 2; kc++){
    half8 f;
    #pragma unroll
    for (int jj = 0; jj < 8; jj++)
      f[jj] = sEl[(kc*32 + lq*8 + jj)*SEP + 16*w + lm];
    bE[kc] = f;
  }

  float4v accA[2] = {{0,0,0,0},{0,0,0,0}};
  #pragma unroll
  for (int kc = 0; kc < 2; kc++){
    #pragma unroll
    for (int mt = 0; mt < 2; mt++){
      half8 a = *(const half8*)&av[(mt*16+lm)*AVP + kc*32 + lq*8];
      accA[mt] = __builtin_amdgcn_mfma_f32_16x16x32_f16(a, bE[kc], accA[mt], 0,0,0);
    }
  }
  {
    int h = 16*w + lm;
    float fr = __expf(-(float)(h & 63) * 0.14391157f);   // ln(1e4)/64
    #pragma unroll
    for (int mt = 0; mt < 2; mt++){
      #pragma unroll
      for (int r = 0; r < 4; r++){
        int tl = mt*16 + lq*4 + r;
        float ang = sVt[tl] * fr;
        float e = (h < 64) ? __sinf(ang) : __cosf(ang);
        vrA[tl*VRP + h] = (_Float16)(accA[mt][r] + e);
      }
    }
  }
  __syncthreads();

  // Phase B: wave owns N-tiles 3w..3w+2; weights/bias pre-scaled for exp2 gates
  half8 bW[3][4]; float biW[3];
  #pragma unroll
  for (int q = 0; q < 3; q++){
    int g = 16*(3*w + q) + lm;
    float sc = (g < 2*H_) ? LOG2E : LOG2E2;
    biW[q] = (bih[g] + (g < 2*H_ ? bhh[g] : 0.0f)) * sc;  // fold b_hh for r,z
    #pragma unroll
    for (int kc = 0; kc < 4; kc++){
      const float* src = &wih[(long)g*H_ + kc*32 + lq*8];
      float4 x0 = *(const float4*)src;
      float4 x1 = *(const float4*)(src+4);
      half8 f;
      f[0]=(_Float16)(x0.x*sc); f[1]=(_Float16)(x0.y*sc); f[2]=(_Float16)(x0.z*sc); f[3]=(_Float16)(x0.w*sc);
      f[4]=(_Float16)(x1.x*sc); f[5]=(_Float16)(x1.y*sc); f[6]=(_Float16)(x1.z*sc); f[7]=(_Float16)(x1.w*sc);
      bW[q][kc] = f;
    }
  }
  float4v cB[2][3];
  #pragma unroll
  for (int mt = 0; mt < 2; mt++)
    #pragma unroll
    for (int q = 0; q < 3; q++) cB[mt][q] = (float4v){0,0,0,0};
  #pragma unroll
  for (int kc = 0; kc < 4; kc++){
    #pragma unroll
    for (int mt = 0; mt < 2; mt++){
      half8 a = *(const half8*)&vrA[(mt*16+lm)*VRP + kc*32 + lq*8];
      #pragma unroll
      for (int q = 0; q < 3; q++)
        cB[mt][q] = __builtin_amdgcn_mfma_f32_16x16x32_f16(a, bW[q][kc], cB[mt][q], 0,0,0);
    }
  }
  #pragma unroll
  for (int mt = 0; mt < 2; mt++){
    #pragma unroll
    for (int q = 0; q < 3; q++){
      int g = 16*(3*w + q) + lm;
      int tb = t0 + mt*16 + lq*4;
      half4v hv;
      hv[0]=(_Float16)(cB[mt][q][0] + biW[q]); hv[1]=(_Float16)(cB[mt][q][1] + biW[q]);
      hv[2]=(_Float16)(cB[mt][q][2] + biW[q]); hv[3]=(_Float16)(cB[mt][q][3] + biW[q]);
      *(half4v*)&gi3[((long)(b*G_ + g))*T_ + tb] = hv;
    }
  }
}

// Sequential GRU v24 (R25) = v22 CHAMPION verbatim: 8-wave N-split, fp8
// K=128 MFMA recurrence. Wave w owns gates j in [16w,16w+16). Per substep:
// ONE mfma_scale_f32_16x16x128_f8f6f4 per gate part (r,z,n) — 3 MFMAs/wave,
// 6/SIMD. h and W_hh in e4m3 stored x16, uniform e8m0 scale 2^-4 per
// operand ((16h)(16w)*2^-8 = h*w); identical lane->k map on A and B so any
// HW k-permutation cancels. Zero-init C (R21 hazard lesson). Gates f32 on
// f16 gi. One LDS-only BAR per step, fp8 hb[2][128] ping-pong, named A/B
// gi prefetch regs.
__global__ void __attribute__((amdgpu_waves_per_eu(2, 2)))
__launch_bounds__(512) gru_k(const _Float16* gi3, const float* whh,
                             const float* bhh, const int* lengths,
                             float* out){
  int b = blockIdx.x;
  int tid = threadIdx.x;
  int w = tid >> 6, l = tid & 63;
  int lq = l >> 4;
  int j = 16*w + (l & 15);       // gate dim owned (valid for all lanes)
  bool gate = (l < 16);
  int len = lengths[b];

  __shared__ __align__(32) unsigned char hb8[2][H_];

  // B-frags (fp8): q=0 r, 1 z, 2 n; byte i of lane (lq,lm) =
  // e4m3(16*sc*W_hh[q*H+16w+lm][lq*32+i])
  int8v bf8[3];
  #pragma unroll
  for (int q = 0; q < 3; q++){
    int row = q*H_ + 16*w + (l & 15);
    float sc16 = ((q == 2) ? LOG2E2 : LOG2E) * 16.0f;
    const float* src = &whh[(long)row*H_ + lq*32];
    int8v f;
    #pragma unroll
    for (int d = 0; d < 8; d++){
      float4 v = *(const float4*)(src + d*4);
      int pk = __builtin_amdgcn_cvt_pk_fp8_f32(v.x*sc16, v.y*sc16, 0, false);
      pk = __builtin_amdgcn_cvt_pk_fp8_f32(v.z*sc16, v.w*sc16, pk, true);
      f[d] = pk;
    }
    bf8[q] = f;
  }
  float bn_ = bhh[2*H_ + j] * LOG2E2;
  const _Float16* pr = gi3 + ((long)b*G_ + j)*T_;
  const _Float16* pz = pr + (long)H_*T_;
  const _Float16* pn = pr + (long)2*H_*T_;

  if (tid < H_){ hb8[0][tid] = 0; hb8[1][tid] = 0; }

  // gi prefetch: named double-buffer registers, static indexing only
  half8 prA, pzA, pnA, prB, pzB, pnB;
  prA = *(const half8*)pr; pzA = *(const half8*)pz; pnA = *(const half8*)pn;
  __syncthreads();   // cold path: full barrier fine

  float hval = 0.0f;

  auto substeps = [&](half8 cr, half8 cz, half8 cn, int c){
    float ho[8];
    #pragma unroll
    for (int i = 0; i < 8; i++){
      const int rp = i & 1;            // read hb8[rp], write hb8[rp^1]
      int8v av = *(const int8v*)&hb8[rp][lq*32];   // 32 B: e4m3(16*h[lq*32..+32])
      float4v c0 = {0,0,0,0}, c1 = {0,0,0,0}, c2 = {0,0,0,0};
      __builtin_amdgcn_s_setprio(1);
      // scale_sel=0, scale=123 (e8m0 2^-4) per operand: (16h)(16w)*2^-8 = h*w
      c0 = __builtin_amdgcn_mfma_scale_f32_16x16x128_f8f6f4(av, bf8[0], c0, 0, 0, 0, 123, 0, 123);
      c1 = __builtin_amdgcn_mfma_scale_f32_16x16x128_f8f6f4(av, bf8[1], c1, 0, 0, 0, 123, 0, 123);
      c2 = __builtin_amdgcn_mfma_scale_f32_16x16x128_f8f6f4(av, bf8[2], c2, 0, 0, 0, 123, 0, 123);
      __builtin_amdgcn_s_setprio(0);
      float r = fsigmoid2((float)cr[i] + c0[0]);
      float z = fsigmoid2((float)cz[i] + c1[0]);
      float n = ftanh2((float)cn[i] + r*(c2[0] + bn_));
      hval = (1.0f - z)*n + z*hval;
      if (gate){
        int hq = __builtin_amdgcn_cvt_pk_fp8_f32(hval*16.0f, hval*16.0f, 0, false);
        hb8[rp^1][j] = (unsigned char)(hq & 0xff);
        ho[i] = (c*8 + i < len) ? hval : 0.0f;
      }
      BAR();
    }
    if (gate){
      long ob = ((long)b*T_ + c*8)*H_ + j;
      #pragma unroll
      for (int i = 0; i < 8; i++) out[ob + (long)i*H_] = ho[i];
    }
  };

  for (int c = 0; c < 32; c += 2){
    {
      int nb = (c+1)*8;
      prB = *(const half8*)(pr+nb); pzB = *(const half8*)(pz+nb); pnB = *(const half8*)(pn+nb);
    }
    substeps(prA, pzA, pnA, c);
    if (c+2 < 32){
      int nb = (c+2)*8;
      prA = *(const half8*)(pr+nb); pzA = *(const half8*)(pz+nb); pnA = *(const half8*)(pn+nb);
    }
    substeps(prB, pzB, pnB, c+1);
  }
}

extern "C" void kernel_launch(void* const* d_in, const int* in_sizes, int n_in,
                              void* d_out, int out_size, void* d_ws, size_t ws_size,
                              hipStream_t stream) {
  char* base = (char*)d_ws;
  size_t off = 0;
  auto alloc = [&](size_t bytes)->void*{
    void* p = base + off; off = (off + bytes + 255) & ~(size_t)255; return p;
  };
  float*     wcol = (float*)alloc((size_t)B_*D_*4);
  _Float16*  gi3  = (_Float16*)alloc((size_t)B_*G_*T_*2);
  if (off > ws_size) return;

  const float* x   = (const float*)d_in[0];
  const float* mm  = (const float*)d_in[1];
  const float* vt  = (const float*)d_in[2];
  const int*   len = (const int*)d_in[4];
  const float* E   = (const float*)d_in[5];
  const float* wih = (const float*)d_in[6];
  const float* whh = (const float*)d_in[7];
  const float* bih = (const float*)d_in[8];
  const float* bhh = (const float*)d_in[9];

  adj_k<<<dim3(B_),dim3(256),0,stream>>>(mm, E, wcol);
  gi_k<<<dim3(256),dim3(512),0,stream>>>(x, mm, vt, E, wih, bih, bhh, wcol, gi3);
  gru_k<<<dim3(B_),dim3(512),0,stream>>>(gi3, whh, bhh, len, (float*)d_out);
}